// Round 9
// baseline (353.212 us; speedup 1.0000x reference)
//
#include <hip/hip_runtime.h>
#include <math.h>
#include <stdint.h>

typedef __attribute__((ext_vector_type(8))) short short8;
typedef __attribute__((ext_vector_type(4))) float f32x4;

__device__ __forceinline__ uint32_t cvt_pk_bf16(float lo, float hi) {
  uint32_t r;
  asm("v_cvt_pk_bf16_f32 %0, %1, %2" : "=v"(r) : "v"(lo), "v"(hi));
  return r;
}

// inverse-distance weight; invalid j has cx=cy=1e30 -> d2 overflows to inf
// -> rcp(inf)=0, so invalid columns contribute exactly 0.
__device__ __forceinline__ float wfun(float hx, float hy, float cx, float cy) {
  float dx = hx - cx, dy = hy - cy;
  float d = __builtin_amdgcn_sqrtf(fmaf(dx, dx, dy * dy));
  return __builtin_amdgcn_rcpf(d + 1e-4f);
}

// ---------------------------------------------------------------------------
// Kernel 1: hp = tanh(batch@W_h + b_h); hx,hy,validf,cxy per row. (verified)
__global__ __launch_bounds__(256) void k_head(
    const float* __restrict__ batch, const float* __restrict__ xywh,
    const float* __restrict__ W_h, const float* __restrict__ b_h,
    float* __restrict__ hp_out, float* __restrict__ hx, float* __restrict__ hy,
    float* __restrict__ validf, float2* __restrict__ cxy, int S, int F) {
  int wid = threadIdx.x >> 6;
  int lane = threadIdx.x & 63;
  int row = blockIdx.x * 4 + wid;
  if (row >= S) return;
  const float4* brow = (const float4*)(batch + (size_t)row * F);
  const float4* wh4 = (const float4*)W_h;  // W_h is [F,2] row-major
  int nf4 = F >> 2;
  float acc0 = 0.f, acc1 = 0.f;
  for (int k4 = lane; k4 < nf4; k4 += 64) {
    float4 b = brow[k4];
    float4 wa = wh4[2 * k4];
    float4 wb = wh4[2 * k4 + 1];
    acc0 += b.x * wa.x + b.y * wa.z + b.z * wb.x + b.w * wb.z;
    acc1 += b.x * wa.y + b.y * wa.w + b.z * wb.y + b.w * wb.w;
  }
  #pragma unroll
  for (int off = 32; off; off >>= 1) {
    acc0 += __shfl_xor(acc0, off, 64);
    acc1 += __shfl_xor(acc1, off, 64);
  }
  if (lane == 0) {
    float hp0 = tanhf(acc0 + b_h[0]);
    float hp1 = tanhf(acc1 + b_h[1]);
    float4 xy = ((const float4*)xywh)[row];
    hp_out[2 * row] = hp0;
    hp_out[2 * row + 1] = hp1;
    hx[row] = hp0 * xy.z * 4.0f + xy.x;  // SIGMA_X = 4
    hy[row] = hp1 * xy.w * 1.0f + xy.y;  // SIGMA_Y = 1
    bool v = (xy.x + xy.y + xy.z + xy.w >= 1e-8f);
    validf[row] = v ? 1.0f : 0.0f;
    cxy[row] = v ? make_float2(xy.x, xy.y) : make_float2(1e30f, 1e30f);
  }
}

// ---------------------------------------------------------------------------
// Kernel 1b: WgT[a][k] = bf16(Wg[k][a])  (verified)
__global__ __launch_bounds__(256) void k_prep_w(
    const float* __restrict__ Wg, uint16_t* __restrict__ WgT, int F, int A) {
  int idx = blockIdx.x * 256 + threadIdx.x;
  int a = idx % A;
  int k0 = (idx / A) * 8;
  if (k0 >= F) return;
  float f[8];
  #pragma unroll
  for (int e = 0; e < 8; ++e) f[e] = Wg[(size_t)(k0 + e) * A + a];
  uint4 v;
  v.x = cvt_pk_bf16(f[0], f[1]);
  v.y = cvt_pk_bf16(f[2], f[3]);
  v.z = cvt_pk_bf16(f[4], f[5]);
  v.w = cvt_pk_bf16(f[6], f[7]);
  *(uint4*)(WgT + (size_t)a * F + k0) = v;
}

// ---------------------------------------------------------------------------
// Kernel 2: targets via bf16 MFMA; tiled output tgt2[jb][a][jj]. (verified)
__global__ __launch_bounds__(256) void k_targets_mfma(
    const float* __restrict__ batch, const uint16_t* __restrict__ WgT,
    const float* __restrict__ bg, uint16_t* __restrict__ tgt2,
    int S, int F, int A) {
  int t = threadIdx.x;
  int lane = t & 63, wid = t >> 6;
  int wm = wid >> 1, wn = wid & 1;
  int i0 = blockIdx.x * 32;
  int row = i0 + wm * 16 + (lane & 15);
  int kch = lane >> 4;
  const float* ab = batch + (size_t)row * F + kch * 8;
  int ncol0 = wn * 128 + (lane & 15);
  const uint16_t* bb = WgT + (size_t)ncol0 * F + kch * 8;

  f32x4 acc[8] = {};
  float4 a0 = *(const float4*)(ab);
  float4 a1 = *(const float4*)(ab + 4);
  short8 bf[8];
  #pragma unroll
  for (int nf = 0; nf < 8; ++nf)
    bf[nf] = *(const short8*)(bb + (size_t)nf * 16 * F);

  for (int k0 = 0; k0 < F; k0 += 32) {
    int kn = (k0 + 32 < F) ? k0 + 32 : 0;  // wrap prefetch (harmless)
    float4 na0 = *(const float4*)(ab + kn);
    float4 na1 = *(const float4*)(ab + kn + 4);
    short8 nbf[8];
    #pragma unroll
    for (int nf = 0; nf < 8; ++nf)
      nbf[nf] = *(const short8*)(bb + kn + (size_t)nf * 16 * F);
    union { short8 s; uint32_t u[4]; } af;
    af.u[0] = cvt_pk_bf16(a0.x, a0.y);
    af.u[1] = cvt_pk_bf16(a0.z, a0.w);
    af.u[2] = cvt_pk_bf16(a1.x, a1.y);
    af.u[3] = cvt_pk_bf16(a1.z, a1.w);
    #pragma unroll
    for (int nf = 0; nf < 8; ++nf)
      acc[nf] = __builtin_amdgcn_mfma_f32_16x16x32_bf16(af.s, bf[nf], acc[nf], 0, 0, 0);
    a0 = na0; a1 = na1;
    #pragma unroll
    for (int nf = 0; nf < 8; ++nf) bf[nf] = nbf[nf];
  }

  int jb = blockIdx.x;
  int rloc = wm * 16 + (lane >> 4) * 4;   // row within tile, mult of 4
  #pragma unroll
  for (int nf = 0; nf < 8; ++nf) {
    int col = ncol0 + nf * 16;
    float b = bg[col];
    float o0 = fmaxf(acc[nf][0] + b, 0.f);
    float o1 = fmaxf(acc[nf][1] + b, 0.f);
    float o2 = fmaxf(acc[nf][2] + b, 0.f);
    float o3 = fmaxf(acc[nf][3] + b, 0.f);
    uint2 pk;
    pk.x = cvt_pk_bf16(o0, o1);
    pk.y = cvt_pk_bf16(o2, o3);
    *(uint2*)(tgt2 + ((size_t)jb * A + col) * 32 + rloc) = pk;
  }
}

// ---------------------------------------------------------------------------
// Kernel 3: out = rownorm(W) @ targets. v8 structure, VALU-stripped:
//  - wn-split w-gen: each wn wave computes HALF of next step's A-frag (4 wfun)
//    and shares via af_lds (ds_write_b64 / ds_read_b128), halving wfun work.
//  - 2-step unroll: compile-time dbuf indices, fixed LDS bases.
//  - pointer-marching globals (no per-step mul / wrap select); peeled last step.
//  - Bt col stride 36 hw (72 B): 16 distinct banks per 16-lane read group.
__global__ __launch_bounds__(1024, 4) void k_gather_v9(
    const uint16_t* __restrict__ tgt2, const float2* __restrict__ cxy,
    const float* __restrict__ hx, const float* __restrict__ hy,
    const float* __restrict__ validf, float* __restrict__ out, int S, int A) {
  __shared__ uint16_t Bt[2][2][128][36];      // 72 KB
  __shared__ uint32_t af_lds[2][2][4][64][4]; // [dbuf][kg][wm][lane][slot] 16 KB
  __shared__ float comb[64][132];             // kg=1 partial acc 33.8 KB
  __shared__ float rs2[2][2][64];             // [kg][wn][row]
  __shared__ float scale_s[64];

  int t = threadIdx.x;
  int lane = t & 63, wid = t >> 6;
  int kg = wid >> 3;                // 0..1
  int sub = wid & 7;
  int wm = sub >> 1, wn = sub & 1;  // 4M x 2N within K-group
  int colhalf = blockIdx.x;         // 0..1
  int i0 = blockIdx.y * 64;
  int mrow = i0 + wm * 16 + (lane & 15);
  int kch = lane >> 4;
  float hx_i = hx[mrow], hy_i = hy[mrow];
  int n0 = wn * 64 + (lane & 15);              // col within block (0..127)
  int nsteps = (S >> 1) / 32;                  // 128 tiles per K-group
  const size_t TSTRIDE = (size_t)A * 32;       // elements per j-tile

  // staging roles: every thread stages 16 B of B per step
  int skg = t >> 9;                 // == kg
  int su = t & 511;
  int scol = su >> 2;               // 0..127
  int skw = su & 3;                 // 0..3
  const uint16_t* gBp = tgt2 + (size_t)(skg * nsteps) * TSTRIDE
                        + (size_t)colhalf * 128 * 32 + scol * 32 + skw * 8;
  // per-wave c pointer: this wave's half (4 float2) of its kch's 8 j's
  const float2* gCp = cxy + (size_t)kg * (S >> 1) + kch * 8 + wn * 4;

  f32x4 acc[4] = {};
  float rs = 0.f;

  // fixed LDS bases
  uint16_t* btW0 = &Bt[0][skg][scol][skw * 8];
  uint16_t* btW1 = &Bt[1][skg][scol][skw * 8];
  uint32_t* afW0 = &af_lds[0][kg][wm][lane][wn * 2];
  uint32_t* afW1 = &af_lds[1][kg][wm][lane][wn * 2];
  const uint32_t* afR0 = &af_lds[0][kg][wm][lane][0];
  const uint32_t* afR1 = &af_lds[1][kg][wm][lane][0];
  const uint16_t* btR0 = &Bt[0][kg][n0][kch * 8];
  const uint16_t* btR1 = &Bt[1][kg][n0][kch * 8];
  const int COLS = 36;  // Bt col stride in halfwords

  // ---- prologue: stage tile 0 into buffer 0 ----
  {
    uint4 gb = *(const uint4*)gBp;  gBp += TSTRIDE;
    float4 ca = *(const float4*)gCp;
    float4 cb = *(const float4*)(gCp + 2);  gCp += 32;
    float wA = wfun(hx_i, hy_i, ca.x, ca.y);
    float wB = wfun(hx_i, hy_i, ca.z, ca.w);
    float wC = wfun(hx_i, hy_i, cb.x, cb.y);
    float wD = wfun(hx_i, hy_i, cb.z, cb.w);
    rs += (wA + wB) + (wC + wD);
    *(uint2*)afW0 = make_uint2(cvt_pk_bf16(wA, wB), cvt_pk_bf16(wC, wD));
    *(uint4*)btW0 = gb;
  }
  __syncthreads();

#define GSTEP(AFR, BTR, AFW, BTW, DO_STAGE)                                    \
  {                                                                            \
    uint4 gb;                                                                  \
    float4 ca, cb;                                                             \
    if (DO_STAGE) {                                                            \
      gb = *(const uint4*)gBp;  gBp += TSTRIDE;                                \
      ca = *(const float4*)gCp;                                                \
      cb = *(const float4*)(gCp + 2);  gCp += 32;                              \
    }                                                                          \
    short8 afr = *(const short8*)(AFR);                                        \
    short8 b0 = *(const short8*)((BTR));                                       \
    short8 b1 = *(const short8*)((BTR) + 16 * COLS);                           \
    short8 b2 = *(const short8*)((BTR) + 32 * COLS);                           \
    short8 b3 = *(const short8*)((BTR) + 48 * COLS);                           \
    acc[0] = __builtin_amdgcn_mfma_f32_16x16x32_bf16(afr, b0, acc[0], 0, 0, 0);\
    acc[1] = __builtin_amdgcn_mfma_f32_16x16x32_bf16(afr, b1, acc[1], 0, 0, 0);\
    acc[2] = __builtin_amdgcn_mfma_f32_16x16x32_bf16(afr, b2, acc[2], 0, 0, 0);\
    acc[3] = __builtin_amdgcn_mfma_f32_16x16x32_bf16(afr, b3, acc[3], 0, 0, 0);\
    if (DO_STAGE) {                                                            \
      float wA = wfun(hx_i, hy_i, ca.x, ca.y);                                 \
      float wB = wfun(hx_i, hy_i, ca.z, ca.w);                                 \
      float wC = wfun(hx_i, hy_i, cb.x, cb.y);                                 \
      float wD = wfun(hx_i, hy_i, cb.z, cb.w);                                 \
      rs += (wA + wB) + (wC + wD);                                             \
      *(uint2*)(AFW) = make_uint2(cvt_pk_bf16(wA, wB), cvt_pk_bf16(wC, wD));   \
      *(uint4*)(BTW) = gb;                                                     \
    }                                                                          \
    __syncthreads();                                                           \
  }

  // main loop: nsteps/2 - 1 double-steps with staging, then a peeled pair
  int npairs = (nsteps >> 1) - 1;
  for (int it = 0; it < npairs; ++it) {
    GSTEP(afR0, btR0, afW1, btW1, true);
    GSTEP(afR1, btR1, afW0, btW0, true);
  }
  GSTEP(afR0, btR0, afW1, btW1, true);   // ts = nsteps-2 (stages last tile)
  GSTEP(afR1, btR1, afW0, btW0, false);  // ts = nsteps-1 (no staging)
#undef GSTEP

  // per-(kg,wn) row sums: reduce over the 4 kch groups
  rs += __shfl_xor(rs, 16, 64);
  rs += __shfl_xor(rs, 32, 64);
  if (lane < 16) rs2[kg][wn][wm * 16 + lane] = rs;

  // kg=1 publishes its partial acc
  if (kg == 1) {
    int mre = wm * 16 + (lane >> 4) * 4;
    #pragma unroll
    for (int r = 0; r < 4; ++r) {
      comb[mre + r][n0]      = acc[0][r];
      comb[mre + r][n0 + 16] = acc[1][r];
      comb[mre + r][n0 + 32] = acc[2][r];
      comb[mre + r][n0 + 48] = acc[3][r];
    }
  }
  __syncthreads();
  if (t < 64) {
    float r = (rs2[0][0][t] + rs2[0][1][t]) + (rs2[1][0][t] + rs2[1][1][t]);
    float v = validf[i0 + t];
    scale_s[t] = (v > 0.f) ? 1.0f / fmaxf(r, 1e-30f) : 0.f;
  }
  __syncthreads();
  if (kg == 0) {
    int mre = wm * 16 + (lane >> 4) * 4;
    #pragma unroll
    for (int r = 0; r < 4; ++r) {
      float s = scale_s[mre + r];
      size_t base = (size_t)(i0 + mre + r) * A + colhalf * 128;
      out[base + n0]      = (acc[0][r] + comb[mre + r][n0]) * s;
      out[base + n0 + 16] = (acc[1][r] + comb[mre + r][n0 + 16]) * s;
      out[base + n0 + 32] = (acc[2][r] + comb[mre + r][n0 + 32]) * s;
      out[base + n0 + 48] = (acc[3][r] + comb[mre + r][n0 + 48]) * s;
    }
  }
}

extern "C" void kernel_launch(void* const* d_in, const int* in_sizes, int n_in,
                              void* d_out, int out_size, void* d_ws, size_t ws_size,
                              hipStream_t stream) {
  // inputs: 0 batch[S,F] 1 xywh[S,4] 2 OW 3 OH 4 actor_weights[S] 5 avg_pos[S,2]
  //         6 W_h[F,2] 7 b_h[2] 8 W_g[F,A] 9 b_g[A] 10 num_person
  const float* batch = (const float*)d_in[0];
  const float* xywh  = (const float*)d_in[1];
  const float* W_h   = (const float*)d_in[6];
  const float* b_h   = (const float*)d_in[7];
  const float* W_g   = (const float*)d_in[8];
  const float* b_g   = (const float*)d_in[9];
  int S = in_sizes[4];
  int F = in_sizes[0] / S;
  int A = in_sizes[9];

  float* out    = (float*)d_out;
  float* out_tw = out;                        // [S,A]
  float* out_hp = out + (size_t)S * A;        // [S,2]

  // workspace: tgt2 bf16 [S/32][A][32], WgT bf16 [A][F], hx/hy/validf, cxy
  uint16_t* tgt2 = (uint16_t*)d_ws;
  uint16_t* WgT  = tgt2 + (size_t)A * S;
  float* hxv = (float*)(WgT + (size_t)A * F);
  float* hyv = hxv + S;
  float* vfv = hyv + S;
  float2* cxyv = (float2*)(vfv + S);

  k_head<<<dim3((S + 3) / 4), 256, 0, stream>>>(batch, xywh, W_h, b_h,
                                                out_hp, hxv, hyv, vfv, cxyv, S, F);
  k_prep_w<<<dim3((A * F / 8 + 255) / 256), 256, 0, stream>>>(W_g, WgT, F, A);
  k_targets_mfma<<<dim3(S / 32), 256, 0, stream>>>(batch, WgT, b_g, tgt2, S, F, A);
  k_gather_v9<<<dim3(2, S / 64), 1024, 0, stream>>>(tgt2, cxyv, hxv, hyv, vfv,
                                                    out_tw, S, A);
}

// Round 11
// 348.693 us; speedup vs baseline: 1.0130x; 1.0130x over previous
//
#include <hip/hip_runtime.h>
#include <math.h>
#include <stdint.h>

typedef __attribute__((ext_vector_type(8))) short short8;
typedef __attribute__((ext_vector_type(4))) float f32x4;

__device__ __forceinline__ uint32_t cvt_pk_bf16(float lo, float hi) {
  uint32_t r;
  asm("v_cvt_pk_bf16_f32 %0, %1, %2" : "=v"(r) : "v"(lo), "v"(hi));
  return r;
}

// inverse-distance weight; invalid j has cx=cy=1e30 -> d2 overflows to inf
// -> rcp(inf)=0, so invalid columns contribute exactly 0.
__device__ __forceinline__ float wfun(float hx, float hy, float cx, float cy) {
  float dx = hx - cx, dy = hy - cy;
  float d = __builtin_amdgcn_sqrtf(fmaf(dx, dx, dy * dy));
  return __builtin_amdgcn_rcpf(d + 1e-4f);
}

// ---------------------------------------------------------------------------
// Kernel 1: hp = tanh(batch@W_h + b_h); hx,hy,validf,cxy per row. (verified)
__global__ __launch_bounds__(256) void k_head(
    const float* __restrict__ batch, const float* __restrict__ xywh,
    const float* __restrict__ W_h, const float* __restrict__ b_h,
    float* __restrict__ hp_out, float* __restrict__ hx, float* __restrict__ hy,
    float* __restrict__ validf, float2* __restrict__ cxy, int S, int F) {
  int wid = threadIdx.x >> 6;
  int lane = threadIdx.x & 63;
  int row = blockIdx.x * 4 + wid;
  if (row >= S) return;
  const float4* brow = (const float4*)(batch + (size_t)row * F);
  const float4* wh4 = (const float4*)W_h;  // W_h is [F,2] row-major
  int nf4 = F >> 2;
  float acc0 = 0.f, acc1 = 0.f;
  for (int k4 = lane; k4 < nf4; k4 += 64) {
    float4 b = brow[k4];
    float4 wa = wh4[2 * k4];
    float4 wb = wh4[2 * k4 + 1];
    acc0 += b.x * wa.x + b.y * wa.z + b.z * wb.x + b.w * wb.z;
    acc1 += b.x * wa.y + b.y * wa.w + b.z * wb.y + b.w * wb.w;
  }
  #pragma unroll
  for (int off = 32; off; off >>= 1) {
    acc0 += __shfl_xor(acc0, off, 64);
    acc1 += __shfl_xor(acc1, off, 64);
  }
  if (lane == 0) {
    float hp0 = tanhf(acc0 + b_h[0]);
    float hp1 = tanhf(acc1 + b_h[1]);
    float4 xy = ((const float4*)xywh)[row];
    hp_out[2 * row] = hp0;
    hp_out[2 * row + 1] = hp1;
    hx[row] = hp0 * xy.z * 4.0f + xy.x;  // SIGMA_X = 4
    hy[row] = hp1 * xy.w * 1.0f + xy.y;  // SIGMA_Y = 1
    bool v = (xy.x + xy.y + xy.z + xy.w >= 1e-8f);
    validf[row] = v ? 1.0f : 0.0f;
    cxy[row] = v ? make_float2(xy.x, xy.y) : make_float2(1e30f, 1e30f);
  }
}

// ---------------------------------------------------------------------------
// Kernel 1b: WgT[a][k] = bf16(Wg[k][a])  (verified)
__global__ __launch_bounds__(256) void k_prep_w(
    const float* __restrict__ Wg, uint16_t* __restrict__ WgT, int F, int A) {
  int idx = blockIdx.x * 256 + threadIdx.x;
  int a = idx % A;
  int k0 = (idx / A) * 8;
  if (k0 >= F) return;
  float f[8];
  #pragma unroll
  for (int e = 0; e < 8; ++e) f[e] = Wg[(size_t)(k0 + e) * A + a];
  uint4 v;
  v.x = cvt_pk_bf16(f[0], f[1]);
  v.y = cvt_pk_bf16(f[2], f[3]);
  v.z = cvt_pk_bf16(f[4], f[5]);
  v.w = cvt_pk_bf16(f[6], f[7]);
  *(uint4*)(WgT + (size_t)a * F + k0) = v;
}

// ---------------------------------------------------------------------------
// Kernel 2: targets via bf16 MFMA; tiled output tgt2[jb][a][jj]. (verified)
__global__ __launch_bounds__(256) void k_targets_mfma(
    const float* __restrict__ batch, const uint16_t* __restrict__ WgT,
    const float* __restrict__ bg, uint16_t* __restrict__ tgt2,
    int S, int F, int A) {
  int t = threadIdx.x;
  int lane = t & 63, wid = t >> 6;
  int wm = wid >> 1, wn = wid & 1;
  int i0 = blockIdx.x * 32;
  int row = i0 + wm * 16 + (lane & 15);
  int kch = lane >> 4;
  const float* ab = batch + (size_t)row * F + kch * 8;
  int ncol0 = wn * 128 + (lane & 15);
  const uint16_t* bb = WgT + (size_t)ncol0 * F + kch * 8;

  f32x4 acc[8] = {};
  float4 a0 = *(const float4*)(ab);
  float4 a1 = *(const float4*)(ab + 4);
  short8 bf[8];
  #pragma unroll
  for (int nf = 0; nf < 8; ++nf)
    bf[nf] = *(const short8*)(bb + (size_t)nf * 16 * F);

  for (int k0 = 0; k0 < F; k0 += 32) {
    int kn = (k0 + 32 < F) ? k0 + 32 : 0;  // wrap prefetch (harmless)
    float4 na0 = *(const float4*)(ab + kn);
    float4 na1 = *(const float4*)(ab + kn + 4);
    short8 nbf[8];
    #pragma unroll
    for (int nf = 0; nf < 8; ++nf)
      nbf[nf] = *(const short8*)(bb + kn + (size_t)nf * 16 * F);
    union { short8 s; uint32_t u[4]; } af;
    af.u[0] = cvt_pk_bf16(a0.x, a0.y);
    af.u[1] = cvt_pk_bf16(a0.z, a0.w);
    af.u[2] = cvt_pk_bf16(a1.x, a1.y);
    af.u[3] = cvt_pk_bf16(a1.z, a1.w);
    #pragma unroll
    for (int nf = 0; nf < 8; ++nf)
      acc[nf] = __builtin_amdgcn_mfma_f32_16x16x32_bf16(af.s, bf[nf], acc[nf], 0, 0, 0);
    a0 = na0; a1 = na1;
    #pragma unroll
    for (int nf = 0; nf < 8; ++nf) bf[nf] = nbf[nf];
  }

  int jb = blockIdx.x;
  int rloc = wm * 16 + (lane >> 4) * 4;   // row within tile, mult of 4
  #pragma unroll
  for (int nf = 0; nf < 8; ++nf) {
    int col = ncol0 + nf * 16;
    float b = bg[col];
    float o0 = fmaxf(acc[nf][0] + b, 0.f);
    float o1 = fmaxf(acc[nf][1] + b, 0.f);
    float o2 = fmaxf(acc[nf][2] + b, 0.f);
    float o3 = fmaxf(acc[nf][3] + b, 0.f);
    uint2 pk;
    pk.x = cvt_pk_bf16(o0, o1);
    pk.y = cvt_pk_bf16(o2, o3);
    *(uint2*)(tgt2 + ((size_t)jb * A + col) * 32 + rloc) = pk;
  }
}

// ---------------------------------------------------------------------------
// Kernel 3: out = rownorm(W) @ targets. v8 body; deltas from v8:
//  (1) Bt col stride 40 -> 36 halfwords (kills 12.6M-cyc bank conflicts).
//  (2) BM 64 -> 32, 512-thread blocks (8 waves = 2kg x 2wm x 2wn), grid
//      (2, S/32) = 512 = 2 independent blocks/CU (cross-block overlap).
//  ROWSUM FIX vs round 10: both wn-waves compute the FULL rowsum, so only
//  wn==0 publishes (rs2[kg][row]); final scale sums the two kg halves only.
__global__ __launch_bounds__(512, 4) void k_gather_v11(
    const uint16_t* __restrict__ tgt2, const float2* __restrict__ cxy,
    const float* __restrict__ hx, const float* __restrict__ hy,
    const float* __restrict__ validf, float* __restrict__ out, int S, int A) {
  __shared__ uint16_t Bt[2][2][128][36];  // [dbuf][kg][col][36hw] 36 KB
  __shared__ float2  Ct[2][2][32];        // [dbuf][kg][jj]        1 KB
  __shared__ float comb[32][132];         // kg=1 partial acc      16.9 KB
  __shared__ float rs2[2][32];            // [kg][row]
  __shared__ float scale_s[32];

  int t = threadIdx.x;
  int lane = t & 63, wid = t >> 6;
  int kg = wid >> 2;                // 0..1
  int sub = wid & 3;
  int wm = sub >> 1, wn = sub & 1;  // 2M x 2N within K-group
  int colhalf = blockIdx.x;         // 0..1
  int i0 = blockIdx.y * 32;
  int mrow = i0 + wm * 16 + (lane & 15);
  int kch = lane >> 4;
  float hx_i = hx[mrow], hy_i = hy[mrow];
  int n0 = wn * 64 + (lane & 15);              // col within block (0..127)
  int nsteps = (S >> 1) / 32;                  // 128 tiles per K-group
  const size_t TSTRIDE = (size_t)A * 32;       // elements per j-tile
  const int COLS = 36;                         // Bt col stride in halfwords

  // staging roles: every thread stages 32 B of B (2 x uint4); t<32 stages c.
  int skg = t >> 8;                 // 0..1
  int su = t & 255;
  int scol = su >> 1;               // 0..127
  int skw = su & 1;                 // 0..1 (16-hw half of the 32-j column)
  const uint16_t* gB0 = tgt2 + (size_t)(skg * nsteps) * TSTRIDE
                        + (size_t)(colhalf * 128 + scol) * 32 + skw * 16;
  const float2* gC0 = cxy + (size_t)(t >> 4) * (S >> 1) + (t & 15) * 2;

  f32x4 acc[4] = {};
  float rs = 0.f;

  // prologue: stage step 0
  {
    uint4 ga = *(const uint4*)(gB0);
    uint4 gb = *(const uint4*)(gB0 + 8);
    *(uint4*)&Bt[0][skg][scol][skw * 16] = ga;
    *(uint4*)&Bt[0][skg][scol][skw * 16 + 8] = gb;
    if (t < 32) {
      float4 gc = *(const float4*)(gC0);
      *(float4*)&Ct[0][t >> 4][(t & 15) * 2] = gc;
    }
  }
  __syncthreads();

  for (int ts = 0; ts < nsteps; ++ts) {
    int cur = ts & 1, nxt = cur ^ 1;
    int tn = (ts + 1 < nsteps) ? ts + 1 : 0;   // wrap stage (harmless)

    // issue next-step global loads into registers (latency hidden by compute)
    uint4 ga = *(const uint4*)(gB0 + (size_t)tn * TSTRIDE);
    uint4 gb = *(const uint4*)(gB0 + (size_t)tn * TSTRIDE + 8);
    float4 gc;
    if (t < 32) gc = *(const float4*)(gC0 + tn * 32);

    // c from LDS (broadcast within 16-lane groups)
    const float2* cp = &Ct[cur][kg][kch * 8];
    float4 c0 = *(const float4*)(cp);
    float4 c1 = *(const float4*)(cp + 2);
    float4 c2 = *(const float4*)(cp + 4);
    float4 c3 = *(const float4*)(cp + 6);

    // B frags from LDS
    const uint16_t* br = &Bt[cur][kg][n0][kch * 8];
    short8 b0 = *(const short8*)(br);
    short8 b1 = *(const short8*)(br + 16 * COLS);
    short8 b2 = *(const short8*)(br + 32 * COLS);
    short8 b3 = *(const short8*)(br + 48 * COLS);

    // 8 w's for this lane's A fragment (row=lane&15, k=(lane>>4)*8+e)
    float w0 = wfun(hx_i, hy_i, c0.x, c0.y);
    float w1 = wfun(hx_i, hy_i, c0.z, c0.w);
    float w2 = wfun(hx_i, hy_i, c1.x, c1.y);
    float w3 = wfun(hx_i, hy_i, c1.z, c1.w);
    float w4 = wfun(hx_i, hy_i, c2.x, c2.y);
    float w5 = wfun(hx_i, hy_i, c2.z, c2.w);
    float w6 = wfun(hx_i, hy_i, c3.x, c3.y);
    float w7 = wfun(hx_i, hy_i, c3.z, c3.w);
    rs += ((w0 + w1) + (w2 + w3)) + ((w4 + w5) + (w6 + w7));
    union { short8 s; uint32_t u[4]; } af;
    af.u[0] = cvt_pk_bf16(w0, w1);
    af.u[1] = cvt_pk_bf16(w2, w3);
    af.u[2] = cvt_pk_bf16(w4, w5);
    af.u[3] = cvt_pk_bf16(w6, w7);

    acc[0] = __builtin_amdgcn_mfma_f32_16x16x32_bf16(af.s, b0, acc[0], 0, 0, 0);
    acc[1] = __builtin_amdgcn_mfma_f32_16x16x32_bf16(af.s, b1, acc[1], 0, 0, 0);
    acc[2] = __builtin_amdgcn_mfma_f32_16x16x32_bf16(af.s, b2, acc[2], 0, 0, 0);
    acc[3] = __builtin_amdgcn_mfma_f32_16x16x32_bf16(af.s, b3, acc[3], 0, 0, 0);

    // write staged data to the other buffer (compiler inserts vmcnt waits)
    *(uint4*)&Bt[nxt][skg][scol][skw * 16] = ga;
    *(uint4*)&Bt[nxt][skg][scol][skw * 16 + 8] = gb;
    if (t < 32) *(float4*)&Ct[nxt][t >> 4][(t & 15) * 2] = gc;
    __syncthreads();
  }

  // per-kg row sums (both wn waves hold the FULL sum -> only wn==0 publishes)
  rs += __shfl_xor(rs, 16, 64);
  rs += __shfl_xor(rs, 32, 64);
  if (wn == 0 && lane < 16) rs2[kg][wm * 16 + lane] = rs;

  // kg=1 publishes its partial acc
  if (kg == 1) {
    int mre = wm * 16 + (lane >> 4) * 4;
    #pragma unroll
    for (int r = 0; r < 4; ++r) {
      comb[mre + r][n0]      = acc[0][r];
      comb[mre + r][n0 + 16] = acc[1][r];
      comb[mre + r][n0 + 32] = acc[2][r];
      comb[mre + r][n0 + 48] = acc[3][r];
    }
  }
  __syncthreads();
  if (t < 32) {
    float r = rs2[0][t] + rs2[1][t];
    float v = validf[i0 + t];
    scale_s[t] = (v > 0.f) ? 1.0f / fmaxf(r, 1e-30f) : 0.f;
  }
  __syncthreads();
  if (kg == 0) {
    int mre = wm * 16 + (lane >> 4) * 4;
    #pragma unroll
    for (int r = 0; r < 4; ++r) {
      float s = scale_s[mre + r];
      size_t base = (size_t)(i0 + mre + r) * A + colhalf * 128;
      out[base + n0]      = (acc[0][r] + comb[mre + r][n0]) * s;
      out[base + n0 + 16] = (acc[1][r] + comb[mre + r][n0 + 16]) * s;
      out[base + n0 + 32] = (acc[2][r] + comb[mre + r][n0 + 32]) * s;
      out[base + n0 + 48] = (acc[3][r] + comb[mre + r][n0 + 48]) * s;
    }
  }
}

extern "C" void kernel_launch(void* const* d_in, const int* in_sizes, int n_in,
                              void* d_out, int out_size, void* d_ws, size_t ws_size,
                              hipStream_t stream) {
  // inputs: 0 batch[S,F] 1 xywh[S,4] 2 OW 3 OH 4 actor_weights[S] 5 avg_pos[S,2]
  //         6 W_h[F,2] 7 b_h[2] 8 W_g[F,A] 9 b_g[A] 10 num_person
  const float* batch = (const float*)d_in[0];
  const float* xywh  = (const float*)d_in[1];
  const float* W_h   = (const float*)d_in[6];
  const float* b_h   = (const float*)d_in[7];
  const float* W_g   = (const float*)d_in[8];
  const float* b_g   = (const float*)d_in[9];
  int S = in_sizes[4];
  int F = in_sizes[0] / S;
  int A = in_sizes[9];

  float* out    = (float*)d_out;
  float* out_tw = out;                        // [S,A]
  float* out_hp = out + (size_t)S * A;        // [S,2]

  // workspace: tgt2 bf16 [S/32][A][32], WgT bf16 [A][F], hx/hy/validf, cxy
  uint16_t* tgt2 = (uint16_t*)d_ws;
  uint16_t* WgT  = tgt2 + (size_t)A * S;
  float* hxv = (float*)(WgT + (size_t)A * F);
  float* hyv = hxv + S;
  float* vfv = hyv + S;
  float2* cxyv = (float2*)(vfv + S);

  k_head<<<dim3((S + 3) / 4), 256, 0, stream>>>(batch, xywh, W_h, b_h,
                                                out_hp, hxv, hyv, vfv, cxyv, S, F);
  k_prep_w<<<dim3((A * F / 8 + 255) / 256), 256, 0, stream>>>(W_g, WgT, F, A);
  k_targets_mfma<<<dim3(S / 32), 256, 0, stream>>>(batch, WgT, b_g, tgt2, S, F, A);
  k_gather_v11<<<dim3(2, S / 32), 512, 0, stream>>>(tgt2, cxyv, hxv, hyv, vfv,
                                                    out_tw, S, A);
}